// Round 6
// baseline (284.705 us; speedup 1.0000x reference)
//
#include <hip/hip_runtime.h>
#include <hip/hip_bf16.h>
#include <cstdint>

#define HIDDEN 1024
#define HEADS 16
#define HDIM 64
#define BATCH 4
#define SEQ 2048
#define MTOT (BATCH * SEQ)   // 8192

typedef __attribute__((ext_vector_type(8))) short bfrag;   // 8 bf16 (A/B frag)
typedef __attribute__((ext_vector_type(4))) float cfrag;   // 4 f32 (C/D frag)
typedef __attribute__((ext_vector_type(4))) float float4v;
typedef __attribute__((ext_vector_type(4))) unsigned short ushort4v;
typedef __attribute__((ext_vector_type(2))) unsigned int uint2v;

#define AS1 __attribute__((address_space(1)))
#define AS3 __attribute__((address_space(3)))

__device__ __forceinline__ void gl_lds16(const void* g, void* l) {
  // async global->LDS, 16B per lane; LDS dest = wave-uniform base + lane*16
  __builtin_amdgcn_global_load_lds((AS1 void*)g, (AS3 void*)l, 16, 0, 0);
}

__device__ __forceinline__ uint16_t f2b(float f) {  // f32 -> bf16 bits, RNE
  union { float f; uint32_t u; } v; v.f = f;
  uint32_t u = v.u;
  return (uint16_t)((u + 0x7FFFu + ((u >> 16) & 1u)) >> 16);
}

// ---------------- kernel 1: fused converts ----------------
// blocks [0,4096): x fp32 -> bf16;  blocks [4096,4864): W -> Wt [N][K] bf16 x3
__global__ __launch_bounds__(256) void cvt_kernel(
    const float* __restrict__ x, const float* __restrict__ W0,
    const float* __restrict__ W1, const float* __restrict__ W2,
    uint16_t* __restrict__ Xb, uint16_t* __restrict__ Wt) {
  int bid = blockIdx.x;
  if (bid < 4096) {
    int i = bid * 256 + threadIdx.x;          // i < 1048576 = MTOT*HIDDEN/8
    float4v a = ((const float4v*)x)[2 * i];
    float4v b = ((const float4v*)x)[2 * i + 1];
    bfrag o;
    o[0] = (short)f2b(a[0]); o[1] = (short)f2b(a[1]);
    o[2] = (short)f2b(a[2]); o[3] = (short)f2b(a[3]);
    o[4] = (short)f2b(b[0]); o[5] = (short)f2b(b[1]);
    o[6] = (short)f2b(b[2]); o[7] = (short)f2b(b[3]);
    ((bfrag*)Xb)[i] = o;
    return;
  }
  int id = bid - 4096;                        // [0,768)
  int z = id >> 8, rem = id & 255;
  const float* W = z == 0 ? W0 : (z == 1 ? W1 : W2);
  uint16_t* out = Wt + (size_t)z * HIDDEN * HIDDEN;
  __shared__ float tile[64][65];
  int n0 = (rem & 15) * 64, k0 = (rem >> 4) * 64;
  int t = threadIdx.x;
  int r = t >> 2, cq = (t & 3) * 16;
#pragma unroll
  for (int i = 0; i < 16; i += 4) {
    float4v v = *(const float4v*)&W[(size_t)(k0 + r) * HIDDEN + n0 + cq + i];
    tile[r][cq + i + 0] = v[0]; tile[r][cq + i + 1] = v[1];
    tile[r][cq + i + 2] = v[2]; tile[r][cq + i + 3] = v[3];
  }
  __syncthreads();
  bfrag o0, o1;
#pragma unroll
  for (int i = 0; i < 8; ++i) o0[i] = (short)f2b(tile[cq + i][r]);
#pragma unroll
  for (int i = 0; i < 8; ++i) o1[i] = (short)f2b(tile[cq + 8 + i][r]);
  *(bfrag*)&out[(size_t)(n0 + r) * HIDDEN + k0 + cq] = o0;
  *(bfrag*)&out[(size_t)(n0 + r) * HIDDEN + k0 + cq + 8] = o1;
}

// ---------------- kernel 2: QKV projection GEMM (2-phase dbuf, XCD-chunked) --
// C[m][n] = sum_k X[m][k] * Wt[n][k] + bias[n]
// which==0: Q bf16 [8192][1024], scaled by 0.125*log2(e) (exp2-domain softmax)
// which==1: K bf16 [8192][1024]
// which==2: V^T bf16 [64 bh][64 d][2048 s]
__global__ __launch_bounds__(256) void gemm_qkv_kernel(
    const uint16_t* __restrict__ X, const uint16_t* __restrict__ Wt,
    const float* __restrict__ b0, const float* __restrict__ b1,
    const float* __restrict__ b2,
    uint16_t* __restrict__ Qo, uint16_t* __restrict__ Ko, uint16_t* __restrict__ Vo) {
  __shared__ uint16_t As[2][128 * 32];
  __shared__ uint16_t Bs[2][128 * 32];

  // XCD-chunked decomposition: 1536 blocks = 8 XCDs x (3 which x 8 m x 8 n).
  // Per-XCD phase working set = X-panel (2MB) + one W (2MB) = one L2.
  int id = blockIdx.x;
  int xcd = id & 7, j = id >> 3;        // j in 0..191
  int which = j >> 6;                    // 0..2, phases of 64
  int r_ = j & 63;
  int m0 = (xcd * 8 + (r_ >> 3)) * 128;
  int n0 = (r_ & 7) * 128;

  const uint16_t* Wp = Wt + (size_t)which * HIDDEN * HIDDEN;
  const float* bias = which == 0 ? b0 : (which == 1 ? b1 : b2);

  int tid = threadIdx.x;
  int wave = tid >> 6, lane = tid & 63;
  int wm = wave >> 1, wn = wave & 1;       // 2x2 wave grid, 64x64 per wave
  int g = lane >> 4, c = lane & 15;
  int sr = lane >> 2;                       // staging: row within 16-row chunk
  int sc = (lane & 3) * 8;                  // staging: k offset (8 bf16 = 16B)

  cfrag acc[4][4];
#pragma unroll
  for (int i = 0; i < 4; ++i)
#pragma unroll
    for (int jj = 0; jj < 4; ++jj) acc[i][jj] = cfrag{0.f, 0.f, 0.f, 0.f};

  // stage K-step kt into LDS buffer `buf` (this wave's 2 row-chunks of A & B)
  auto STAGE = [&](int buf, int kt) {
    int kc = kt * 32 + sc;
#pragma unroll
    for (int i = 0; i < 2; ++i) {
      int rowA = (i * 4 + wave) * 16;  // wave-uniform
      gl_lds16(&X[(size_t)(m0 + rowA + sr) * HIDDEN + kc], &As[buf][rowA * 32]);
      gl_lds16(&Wp[(size_t)(n0 + rowA + sr) * HIDDEN + kc], &Bs[buf][rowA * 32]);
    }
  };

  STAGE(0, 0);
  __syncthreads();                      // drain vmcnt -> tile 0 ready
  int cur = 0;

  for (int kt = 0; kt < HIDDEN / 32; ++kt) {
    if (kt < HIDDEN / 32 - 1) STAGE(cur ^ 1, kt + 1);  // hide under compute
    bfrag af[4], bf[4];
#pragma unroll
    for (int mt = 0; mt < 4; ++mt)
      af[mt] = *(const bfrag*)&As[cur][(wm * 64 + mt * 16 + c) * 32 + g * 8];
#pragma unroll
    for (int nt = 0; nt < 4; ++nt)
      bf[nt] = *(const bfrag*)&Bs[cur][(wn * 64 + nt * 16 + c) * 32 + g * 8];
    __builtin_amdgcn_s_setprio(1);
#pragma unroll
    for (int mt = 0; mt < 4; ++mt)
#pragma unroll
      for (int nt = 0; nt < 4; ++nt)
        acc[mt][nt] = __builtin_amdgcn_mfma_f32_16x16x32_bf16(af[mt], bf[nt],
                                                              acc[mt][nt], 0, 0, 0);
    __builtin_amdgcn_s_setprio(0);
    __syncthreads();  // reads done + this iter's stage drained (vmcnt 0)
    cur ^= 1;
  }

  if (which == 2) {
    // V^T epilogue: [bh][d][s]; 4 consecutive s per fragment -> ushort4 store
    int bb_ = m0 >> 11;                 // batch (m0 128-aligned, 2048%128==0)
    int s0 = (m0 & 2047) + wm * 64;
#pragma unroll
    for (int nt = 0; nt < 4; ++nt) {
      int n = n0 + wn * 64 + nt * 16 + c;
      int h = n >> 6, d = n & 63;
      float bb = bias[n];
      size_t base = ((size_t)(bb_ * 16 + h) * 64 + d) * SEQ;
#pragma unroll
      for (int mt = 0; mt < 4; ++mt) {
        int s = s0 + mt * 16 + g * 4;
        ushort4v pk;
        pk[0] = f2b(acc[mt][nt][0] + bb);
        pk[1] = f2b(acc[mt][nt][1] + bb);
        pk[2] = f2b(acc[mt][nt][2] + bb);
        pk[3] = f2b(acc[mt][nt][3] + bb);
        *(ushort4v*)&Vo[base + s] = pk;
      }
    }
  } else {
    uint16_t* out = which == 0 ? Qo : Ko;
    // Q: fold softmax scale AND log2(e) so scores arrive in exp2 domain
    float sc_ = which == 0 ? 0.125f * 1.44269504088896f : 1.0f;
#pragma unroll
    for (int nt = 0; nt < 4; ++nt) {
      int n = n0 + wn * 64 + nt * 16 + c;
      float bb = bias[n];
#pragma unroll
      for (int mt = 0; mt < 4; ++mt) {
        int mb = m0 + wm * 64 + mt * 16 + g * 4;
#pragma unroll
        for (int r = 0; r < 4; ++r)
          out[(size_t)(mb + r) * HIDDEN + n] = f2b((acc[mt][nt][r] + bb) * sc_);
      }
    }
  }
}

// ---------------- kernel 3: flash attention (transposed, exp2, no fences) ----
// Q,K bf16 [8192][1024]; VT bf16 [64][64][2048]; out fp32 [8192][1024]
// S^T = mfma(K,Q) in log2 domain; ctx^T = mfma(V^T,P). Lane owns q-row q=c.
__global__ __launch_bounds__(256, 4) void attn_kernel(
    const uint16_t* __restrict__ Q, const uint16_t* __restrict__ K,
    const uint16_t* __restrict__ VT, float* __restrict__ out) {
  __shared__ uint16_t Ks[2][64 * 64];    // K tile, XOR-swizzled content
  __shared__ uint16_t Vs[2][64 * 64];    // V^T tile [d][s], XOR-swizzled content
  __shared__ __align__(16) uint16_t Pl[4][16][64];  // per-wave P [q][kv], XOR-swz

  // XCD-aware swizzle: each XCD's resident blocks cover 8 heads (KV=4MB=L2)
  int bid = blockIdx.x;
  int wg = (bid & 7) * 256 + (bid >> 3);
  int bh = wg >> 5, qt = wg & 31;
  int b = bh >> 4, h = bh & 15;
  int tid = threadIdx.x, wave = tid >> 6, lane = tid & 63;
  int g = lane >> 4, c = lane & 15;
  size_t rowb = (size_t)b * SEQ;
  int colb = h * HDIM;
  const uint16_t* Kh = K + rowb * HIDDEN + colb;          // [s][d] stride 1024
  const uint16_t* Vh = VT + (size_t)bh * HDIM * SEQ;      // [d][s] stride 2048

  // staging: lane covers 16B; pre-swizzled global col so the LINEAR
  // global_load_lds write lands XOR-swizzled (rule #21 both-sides)
  int r8 = lane >> 3, c8 = lane & 7;
  int scol = ((c8 ^ r8) << 3);           // element offset 0..56
  int sbrow = (wave & 1) * 32;           // this wave's 4 calls start here

  // Q fragment (B-operand: col=lane&15=q, k = g*8..)
  int qrow = qt * 64 + wave * 16 + c;
  bfrag aq[2];
  aq[0] = *(const bfrag*)&Q[(rowb + qrow) * HIDDEN + colb + g * 8];
  aq[1] = *(const bfrag*)&Q[(rowb + qrow) * HIDDEN + colb + 32 + g * 8];

  float mr = -INFINITY, lr = 0.f;        // per-lane state; lr = PARTIAL row sum
  cfrag oacc[4];                         // ctx^T: d = dt*16+g*4+r, q = c
#pragma unroll
  for (int dt = 0; dt < 4; ++dt) oacc[dt] = cfrag{0.f, 0.f, 0.f, 0.f};

  // prologue: stage tile 0 into buf 0 (waves 0-1: K rows, waves 2-3: V rows)
  if (wave < 2) {
#pragma unroll
    for (int j = 0; j < 4; ++j) {
      int rl = sbrow + j * 8;
      gl_lds16(&Kh[(size_t)(rl + r8) * HIDDEN + scol], &Ks[0][rl * 64]);
    }
  } else {
#pragma unroll
    for (int j = 0; j < 4; ++j) {
      int rl = sbrow + j * 8;
      gl_lds16(&Vh[(size_t)(rl + r8) * SEQ + scol], &Vs[0][rl * 64]);
    }
  }
  __syncthreads();  // compiler drains vmcnt before barrier -> tile 0 ready

  int cur = 0;
  int sw = (c & 7) << 4;                 // read-side byte swizzle (K/V and P)
  uint8_t* Pb = (uint8_t*)Pl + wave * 2048 + c * 128;  // this lane's P row

  for (int t = 0; t < 32; ++t) {
    int j0 = t * 64;
    // issue next-tile stage first; latency hides under this tile's compute
    if (t < 31) {
      int jn = j0 + 64;
      if (wave < 2) {
#pragma unroll
        for (int j = 0; j < 4; ++j) {
          int rl = sbrow + j * 8;
          gl_lds16(&Kh[(size_t)(jn + rl + r8) * HIDDEN + scol],
                   &Ks[cur ^ 1][rl * 64]);
        }
      } else {
#pragma unroll
        for (int j = 0; j < 4; ++j) {
          int rl = sbrow + j * 8;
          gl_lds16(&Vh[(size_t)(rl + r8) * SEQ + jn + scol],
                   &Vs[cur ^ 1][rl * 64]);
        }
      }
    }

    const uint8_t* Kbuf = (const uint8_t*)Ks[cur];
    const uint8_t* Vbuf = (const uint8_t*)Vs[cur];

    // S^T = K @ Q^T from swizzled LDS; lane holds kv = nt*16+g*4+r, q = c
    cfrag s[4];
#pragma unroll
    for (int nt = 0; nt < 4; ++nt) s[nt] = cfrag{0.f, 0.f, 0.f, 0.f};
    __builtin_amdgcn_s_setprio(1);
#pragma unroll
    for (int kb = 0; kb < 2; ++kb) {
#pragma unroll
      for (int nt = 0; nt < 4; ++nt) {
        int off = ((nt * 16 + c) * 128 + kb * 64 + g * 16) ^ sw;
        bfrag bk = *(const bfrag*)(Kbuf + off);
        s[nt] = __builtin_amdgcn_mfma_f32_16x16x32_bf16(bk, aq[kb], s[nt], 0, 0, 0);
      }
    }
    __builtin_amdgcn_s_setprio(0);

    // online softmax (log2 domain); max tree as max3 chain (7x v_max3 + 1 max)
    float mx = fmaxf(fmaxf(s[0][0], s[0][1]), s[0][2]);
    mx = fmaxf(fmaxf(mx, s[0][3]), s[1][0]);
    mx = fmaxf(fmaxf(mx, s[1][1]), s[1][2]);
    mx = fmaxf(fmaxf(mx, s[1][3]), s[2][0]);
    mx = fmaxf(fmaxf(mx, s[2][1]), s[2][2]);
    mx = fmaxf(fmaxf(mx, s[2][3]), s[3][0]);
    mx = fmaxf(fmaxf(mx, s[3][1]), s[3][2]);
    mx = fmaxf(mx, s[3][3]);
    mx = fmaxf(mx, __shfl_xor(mx, 16, 64));
    mx = fmaxf(mx, __shfl_xor(mx, 32, 64));   // mx uniform across g-quartet
    if (mx > mr + 8.0f) {                     // defer-max (T13), log2 units
      float alpha = __builtin_amdgcn_exp2f(mr - mx);
      lr *= alpha;
#pragma unroll
      for (int dt = 0; dt < 4; ++dt)
#pragma unroll
        for (int r = 0; r < 4; ++r) oacc[dt][r] *= alpha;
      mr = mx;
    }
    float ps = 0.f;
#pragma unroll
    for (int nt = 0; nt < 4; ++nt) {
#pragma unroll
      for (int r = 0; r < 4; ++r)
        s[nt][r] = __builtin_amdgcn_exp2f(s[nt][r] - mr);
      ps += (s[nt][0] + s[nt][1]) + (s[nt][2] + s[nt][3]);
    }
    lr += ps;   // partial (this lane's 16 kv); cross-g reduce at epilogue

    // pack P -> bf16 pairs (T12 cvt_pk) and store 8B per nt, XOR-swizzled
#pragma unroll
    for (int nt = 0; nt < 4; ++nt) {
      uint32_t w0, w1;
      asm("v_cvt_pk_bf16_f32 %0, %1, %2" : "=v"(w0) : "v"(s[nt][0]), "v"(s[nt][1]));
      asm("v_cvt_pk_bf16_f32 %0, %1, %2" : "=v"(w1) : "v"(s[nt][2]), "v"(s[nt][3]));
      uint2v pw; pw[0] = w0; pw[1] = w1;
      *(uint2v*)(Pb + ((nt * 32 + g * 8) ^ sw)) = pw;
    }
    // no explicit fence: same-wave DS ops are in-order; compiler inserts the
    // precise lgkmcnt for the may-alias write->read pair.

    // PV transposed: ctx^T += V^T @ P^T; A = V^T rows, B = P rows (q=c)
    __builtin_amdgcn_s_setprio(1);
#pragma unroll
    for (int kb = 0; kb < 2; ++kb) {
      bfrag ap = *(const bfrag*)(Pb + ((kb * 64 + g * 16) ^ sw));
#pragma unroll
      for (int dt = 0; dt < 4; ++dt) {
        int off = ((dt * 16 + c) * 128 + kb * 64 + g * 16) ^ sw;
        bfrag bv = *(const bfrag*)(Vbuf + off);
        oacc[dt] = __builtin_amdgcn_mfma_f32_16x16x32_bf16(bv, ap, oacc[dt], 0, 0, 0);
      }
    }
    __builtin_amdgcn_s_setprio(0);

    __syncthreads();  // drains this wave's stage vmcnt; next tile ready
    cur ^= 1;
  }

  // epilogue: finish l reduction (2 shfls), write q-row c as float4s
  lr += __shfl_xor(lr, 16, 64);
  lr += __shfl_xor(lr, 32, 64);
  float inv = 1.0f / lr;
  size_t orow = rowb + (size_t)qt * 64 + wave * 16 + c;
#pragma unroll
  for (int dt = 0; dt < 4; ++dt) {
    float4v o;
    o[0] = oacc[dt][0] * inv; o[1] = oacc[dt][1] * inv;
    o[2] = oacc[dt][2] * inv; o[3] = oacc[dt][3] * inv;
    *(float4v*)&out[orow * HIDDEN + colb + dt * 16 + g * 4] = o;
  }
}

extern "C" void kernel_launch(void* const* d_in, const int* in_sizes, int n_in,
                              void* d_out, int out_size, void* d_ws, size_t ws_size,
                              hipStream_t stream) {
  const float* x  = (const float*)d_in[0];
  const float* Wq = (const float*)d_in[1];
  const float* bq = (const float*)d_in[2];
  const float* Wk = (const float*)d_in[3];
  const float* bk = (const float*)d_in[4];
  const float* Wv = (const float*)d_in[5];
  const float* bv = (const float*)d_in[6];
  float* out = (float*)d_out;

  uint8_t* ws = (uint8_t*)d_ws;
  const size_t XB = 0;
  const size_t WT = XB + (size_t)MTOT * HIDDEN * 2;        // 16 MB
  const size_t QB = WT + (size_t)3 * HIDDEN * HIDDEN * 2;  // +6 MB
  const size_t KB = QB + (size_t)MTOT * HIDDEN * 2;
  const size_t VB = KB + (size_t)MTOT * HIDDEN * 2;        // total ~70 MB
  uint16_t* Xb = (uint16_t*)(ws + XB);
  uint16_t* Wt = (uint16_t*)(ws + WT);
  uint16_t* Qb = (uint16_t*)(ws + QB);
  uint16_t* Kb = (uint16_t*)(ws + KB);
  uint16_t* Vb = (uint16_t*)(ws + VB);   // V^T [64][64][2048]

  cvt_kernel<<<dim3(4096 + 768), 256, 0, stream>>>(x, Wq, Wk, Wv, Xb, Wt);
  gemm_qkv_kernel<<<dim3(1536), 256, 0, stream>>>(Xb, Wt, bq, bk, bv, Qb, Kb, Vb);
  attn_kernel<<<dim3(2048), 256, 0, stream>>>(Qb, Kb, Vb, out);
}

// Round 7
// 272.868 us; speedup vs baseline: 1.0434x; 1.0434x over previous
//
#include <hip/hip_runtime.h>
#include <hip/hip_bf16.h>
#include <cstdint>

#define HIDDEN 1024
#define HEADS 16
#define HDIM 64
#define BATCH 4
#define SEQ 2048
#define MTOT (BATCH * SEQ)   // 8192

typedef __attribute__((ext_vector_type(8))) short bfrag;   // 8 bf16 (A/B frag)
typedef __attribute__((ext_vector_type(4))) float cfrag;   // 4 f32 (C/D frag)
typedef __attribute__((ext_vector_type(4))) float float4v;
typedef __attribute__((ext_vector_type(4))) unsigned short ushort4v;
typedef __attribute__((ext_vector_type(2))) unsigned int uint2v;

#define AS1 __attribute__((address_space(1)))
#define AS3 __attribute__((address_space(3)))

__device__ __forceinline__ void gl_lds16(const void* g, void* l) {
  // async global->LDS, 16B per lane; LDS dest = wave-uniform base + lane*16
  __builtin_amdgcn_global_load_lds((AS1 void*)g, (AS3 void*)l, 16, 0, 0);
}

__device__ __forceinline__ uint16_t f2b(float f) {  // f32 -> bf16 bits, RNE
  union { float f; uint32_t u; } v; v.f = f;
  uint32_t u = v.u;
  return (uint16_t)((u + 0x7FFFu + ((u >> 16) & 1u)) >> 16);
}

// ---------------- kernel 1: fused converts ----------------
// blocks [0,4096): x fp32 -> bf16;  blocks [4096,4864): W -> Wt [N][K] bf16 x3
__global__ __launch_bounds__(256) void cvt_kernel(
    const float* __restrict__ x, const float* __restrict__ W0,
    const float* __restrict__ W1, const float* __restrict__ W2,
    uint16_t* __restrict__ Xb, uint16_t* __restrict__ Wt) {
  int bid = blockIdx.x;
  if (bid < 4096) {
    int i = bid * 256 + threadIdx.x;          // i < 1048576 = MTOT*HIDDEN/8
    float4v a = ((const float4v*)x)[2 * i];
    float4v b = ((const float4v*)x)[2 * i + 1];
    bfrag o;
    o[0] = (short)f2b(a[0]); o[1] = (short)f2b(a[1]);
    o[2] = (short)f2b(a[2]); o[3] = (short)f2b(a[3]);
    o[4] = (short)f2b(b[0]); o[5] = (short)f2b(b[1]);
    o[6] = (short)f2b(b[2]); o[7] = (short)f2b(b[3]);
    ((bfrag*)Xb)[i] = o;
    return;
  }
  int id = bid - 4096;                        // [0,768)
  int z = id >> 8, rem = id & 255;
  const float* W = z == 0 ? W0 : (z == 1 ? W1 : W2);
  uint16_t* out = Wt + (size_t)z * HIDDEN * HIDDEN;
  __shared__ float tile[64][65];
  int n0 = (rem & 15) * 64, k0 = (rem >> 4) * 64;
  int t = threadIdx.x;
  int r = t >> 2, cq = (t & 3) * 16;
#pragma unroll
  for (int i = 0; i < 16; i += 4) {
    float4v v = *(const float4v*)&W[(size_t)(k0 + r) * HIDDEN + n0 + cq + i];
    tile[r][cq + i + 0] = v[0]; tile[r][cq + i + 1] = v[1];
    tile[r][cq + i + 2] = v[2]; tile[r][cq + i + 3] = v[3];
  }
  __syncthreads();
  bfrag o0, o1;
#pragma unroll
  for (int i = 0; i < 8; ++i) o0[i] = (short)f2b(tile[cq + i][r]);
#pragma unroll
  for (int i = 0; i < 8; ++i) o1[i] = (short)f2b(tile[cq + 8 + i][r]);
  *(bfrag*)&out[(size_t)(n0 + r) * HIDDEN + k0 + cq] = o0;
  *(bfrag*)&out[(size_t)(n0 + r) * HIDDEN + k0 + cq + 8] = o1;
}

// ---------------- kernel 2: QKV projection GEMM (m97 structure, z-grid) ------
// C[m][n] = sum_k X[m][k] * Wt[n][k] + bias[n]
// which==0: Q bf16 [8192][1024], scaled by 0.125*log2(e) (exp2-domain softmax)
// which==1: K bf16 [8192][1024]
// which==2: V^T bf16 [64 bh][64 d][2048 s]
__global__ __launch_bounds__(256) void gemm_qkv_kernel(
    const uint16_t* __restrict__ X, const uint16_t* __restrict__ Wt,
    const float* __restrict__ b0, const float* __restrict__ b1,
    const float* __restrict__ b2,
    uint16_t* __restrict__ Qo, uint16_t* __restrict__ Ko, uint16_t* __restrict__ Vo) {
  __shared__ uint16_t As[128 * 32];
  __shared__ uint16_t Bs[128 * 32];
  int which = blockIdx.z;
  const uint16_t* Wp = Wt + (size_t)which * HIDDEN * HIDDEN;
  const float* bias = which == 0 ? b0 : (which == 1 ? b1 : b2);

  int m0 = blockIdx.x * 128, n0 = blockIdx.y * 128;
  int tid = threadIdx.x;
  int wave = tid >> 6, lane = tid & 63;
  int wm = wave >> 1, wn = wave & 1;       // 2x2 wave grid, 64x64 per wave
  int g = lane >> 4, c = lane & 15;
  int sr = lane >> 2;                       // staging: row within 16-row chunk
  int sc = (lane & 3) * 8;                  // staging: k offset (8 bf16 = 16B)

  cfrag acc[4][4];
#pragma unroll
  for (int i = 0; i < 4; ++i)
#pragma unroll
    for (int jj = 0; jj < 4; ++jj) acc[i][jj] = cfrag{0.f, 0.f, 0.f, 0.f};

  for (int kt = 0; kt < HIDDEN / 32; ++kt) {
    int kc = kt * 32 + sc;
#pragma unroll
    for (int i = 0; i < 2; ++i) {
      int rowA = (i * 4 + wave) * 16;  // wave-uniform
      gl_lds16(&X[(size_t)(m0 + rowA + sr) * HIDDEN + kc], &As[rowA * 32]);
      gl_lds16(&Wp[(size_t)(n0 + rowA + sr) * HIDDEN + kc], &Bs[rowA * 32]);
    }
    __syncthreads();  // vmcnt(0) drained before barrier -> LDS ready
    bfrag af[4], bf[4];
#pragma unroll
    for (int mt = 0; mt < 4; ++mt)
      af[mt] = *(const bfrag*)&As[(wm * 64 + mt * 16 + c) * 32 + g * 8];
#pragma unroll
    for (int nt = 0; nt < 4; ++nt)
      bf[nt] = *(const bfrag*)&Bs[(wn * 64 + nt * 16 + c) * 32 + g * 8];
#pragma unroll
    for (int mt = 0; mt < 4; ++mt)
#pragma unroll
      for (int nt = 0; nt < 4; ++nt)
        acc[mt][nt] = __builtin_amdgcn_mfma_f32_16x16x32_bf16(af[mt], bf[nt],
                                                              acc[mt][nt], 0, 0, 0);
    __syncthreads();  // all waves done with LDS before next stage
  }

  if (which == 2) {
    // V^T epilogue: [bh][d][s]; 4 consecutive s per fragment -> ushort4 store
    int bb_ = m0 >> 11;                 // batch (m0 128-aligned, 2048%128==0)
    int s0 = (m0 & 2047) + wm * 64;
#pragma unroll
    for (int nt = 0; nt < 4; ++nt) {
      int n = n0 + wn * 64 + nt * 16 + c;
      int h = n >> 6, d = n & 63;
      float bb = bias[n];
      size_t base = ((size_t)(bb_ * 16 + h) * 64 + d) * SEQ;
#pragma unroll
      for (int mt = 0; mt < 4; ++mt) {
        int s = s0 + mt * 16 + g * 4;
        ushort4v pk;
        pk[0] = f2b(acc[mt][nt][0] + bb);
        pk[1] = f2b(acc[mt][nt][1] + bb);
        pk[2] = f2b(acc[mt][nt][2] + bb);
        pk[3] = f2b(acc[mt][nt][3] + bb);
        *(ushort4v*)&Vo[base + s] = pk;
      }
    }
  } else {
    uint16_t* out = which == 0 ? Qo : Ko;
    // Q: fold softmax scale AND log2(e) so scores arrive in exp2 domain
    float sc_ = which == 0 ? 0.125f * 1.44269504088896f : 1.0f;
#pragma unroll
    for (int nt = 0; nt < 4; ++nt) {
      int n = n0 + wn * 64 + nt * 16 + c;
      float bb = bias[n];
#pragma unroll
      for (int mt = 0; mt < 4; ++mt) {
        int mb = m0 + wm * 64 + mt * 16 + g * 4;
#pragma unroll
        for (int r = 0; r < 4; ++r)
          out[(size_t)(mb + r) * HIDDEN + n] = f2b((acc[mt][nt][r] + bb) * sc_);
      }
    }
  }
}

// ---------------- kernel 3: flash attention (QBLK=128, transposed, exp2) -----
// Q,K bf16 [8192][1024]; VT bf16 [64][64][2048]; out fp32 [8192][1024]
// 4 waves x 32 q-rows each; S^T = mfma(K,Q) log2-domain; ctx^T = mfma(V^T,P).
// Lane owns q-rows {c, 16+c} of its wave; softmax in-lane + 2 shfls.
__global__ __launch_bounds__(256, 3) void attn_kernel(
    const uint16_t* __restrict__ Q, const uint16_t* __restrict__ K,
    const uint16_t* __restrict__ VT, float* __restrict__ out) {
  __shared__ uint16_t Ks[2][64 * 64];    // K tile, XOR-swizzled content
  __shared__ uint16_t Vs[2][64 * 64];    // V^T tile [d][s], XOR-swizzled content
  __shared__ __align__(16) uint16_t Pl[4][32][64];  // per-wave P [q][kv], XOR-swz

  // XCD-aware swizzle: 1024 blocks -> each XCD covers 4 heads (KV L2-resident)
  int bid = blockIdx.x;
  int wg = (bid & 7) * 128 + (bid >> 3);
  int bh = wg >> 4, qt = wg & 15;
  int b = bh >> 4, h = bh & 15;
  int tid = threadIdx.x, wave = tid >> 6, lane = tid & 63;
  int g = lane >> 4, c = lane & 15;
  size_t rowb = (size_t)b * SEQ;
  int colb = h * HDIM;
  const uint16_t* Kh = K + rowb * HIDDEN + colb;          // [s][d] stride 1024
  const uint16_t* Vh = VT + (size_t)bh * HDIM * SEQ;      // [d][s] stride 2048

  // staging: lane covers 16B; pre-swizzled global col so the LINEAR
  // global_load_lds write lands XOR-swizzled (rule #21 both-sides)
  int r8 = lane >> 3, c8 = lane & 7;
  int scol = ((c8 ^ r8) << 3);           // element offset 0..56
  int sbrow = (wave & 1) * 32;           // this wave's 4 calls start here

  // Q fragments (B-operand: col=lane&15=q, k=g*8..) for both q-halves
  int qrow = qt * 128 + wave * 32 + c;
  bfrag aq0[2], aq1[2];
#pragma unroll
  for (int kb = 0; kb < 2; ++kb) {
    aq0[kb] = *(const bfrag*)&Q[(rowb + qrow) * HIDDEN + colb + kb * 32 + g * 8];
    aq1[kb] = *(const bfrag*)&Q[(rowb + qrow + 16) * HIDDEN + colb + kb * 32 + g * 8];
  }

  float mr0 = -INFINITY, lr0 = 0.f;      // per-lane state, q-half 0 (row c)
  float mr1 = -INFINITY, lr1 = 0.f;      // q-half 1 (row 16+c)
  cfrag oacc0[4], oacc1[4];              // ctx^T: d = dt*16+g*4+r
#pragma unroll
  for (int dt = 0; dt < 4; ++dt) {
    oacc0[dt] = cfrag{0.f, 0.f, 0.f, 0.f};
    oacc1[dt] = cfrag{0.f, 0.f, 0.f, 0.f};
  }

  // prologue: stage tile 0 into buf 0 (waves 0-1: K rows, waves 2-3: V rows)
  if (wave < 2) {
#pragma unroll
    for (int j = 0; j < 4; ++j) {
      int rl = sbrow + j * 8;
      gl_lds16(&Kh[(size_t)(rl + r8) * HIDDEN + scol], &Ks[0][rl * 64]);
    }
  } else {
#pragma unroll
    for (int j = 0; j < 4; ++j) {
      int rl = sbrow + j * 8;
      gl_lds16(&Vh[(size_t)(rl + r8) * SEQ + scol], &Vs[0][rl * 64]);
    }
  }
  __syncthreads();  // compiler drains vmcnt before barrier -> tile 0 ready

  int cur = 0;
  int sw = (c & 7) << 4;                 // read-side byte swizzle (K/V and P)
  uint8_t* Pb0 = (uint8_t*)Pl + wave * 4096 + c * 128;        // P row q=c
  uint8_t* Pb1 = Pb0 + 16 * 128;                              // P row q=16+c

  for (int t = 0; t < 32; ++t) {
    int j0 = t * 64;
    // issue next-tile stage first; latency hides under this tile's compute
    if (t < 31) {
      int jn = j0 + 64;
      if (wave < 2) {
#pragma unroll
        for (int j = 0; j < 4; ++j) {
          int rl = sbrow + j * 8;
          gl_lds16(&Kh[(size_t)(jn + rl + r8) * HIDDEN + scol],
                   &Ks[cur ^ 1][rl * 64]);
        }
      } else {
#pragma unroll
        for (int j = 0; j < 4; ++j) {
          int rl = sbrow + j * 8;
          gl_lds16(&Vh[(size_t)(rl + r8) * SEQ + jn + scol],
                   &Vs[cur ^ 1][rl * 64]);
        }
      }
    }

    const uint8_t* Kbuf = (const uint8_t*)Ks[cur];
    const uint8_t* Vbuf = (const uint8_t*)Vs[cur];

    // S^T = K @ Q^T, both q-halves; K-frag read once, used twice
    cfrag s0[4], s1[4];
#pragma unroll
    for (int nt = 0; nt < 4; ++nt) {
      s0[nt] = cfrag{0.f, 0.f, 0.f, 0.f};
      s1[nt] = cfrag{0.f, 0.f, 0.f, 0.f};
    }
    __builtin_amdgcn_s_setprio(1);
#pragma unroll
    for (int kb = 0; kb < 2; ++kb) {
#pragma unroll
      for (int nt = 0; nt < 4; ++nt) {
        int off = ((nt * 16 + c) * 128 + kb * 64 + g * 16) ^ sw;
        bfrag bk = *(const bfrag*)(Kbuf + off);
        s0[nt] = __builtin_amdgcn_mfma_f32_16x16x32_bf16(bk, aq0[kb], s0[nt], 0, 0, 0);
        s1[nt] = __builtin_amdgcn_mfma_f32_16x16x32_bf16(bk, aq1[kb], s1[nt], 0, 0, 0);
      }
    }
    __builtin_amdgcn_s_setprio(0);

    // ---- softmax q-half 0 (log2 domain) ----
    {
      float mx = fmaxf(fmaxf(s0[0][0], s0[0][1]), s0[0][2]);
      mx = fmaxf(fmaxf(mx, s0[0][3]), s0[1][0]);
      mx = fmaxf(fmaxf(mx, s0[1][1]), s0[1][2]);
      mx = fmaxf(fmaxf(mx, s0[1][3]), s0[2][0]);
      mx = fmaxf(fmaxf(mx, s0[2][1]), s0[2][2]);
      mx = fmaxf(fmaxf(mx, s0[2][3]), s0[3][0]);
      mx = fmaxf(fmaxf(mx, s0[3][1]), s0[3][2]);
      mx = fmaxf(mx, s0[3][3]);
      mx = fmaxf(mx, __shfl_xor(mx, 16, 64));
      mx = fmaxf(mx, __shfl_xor(mx, 32, 64));
      if (mx > mr0 + 8.0f) {                   // defer-max (T13)
        float alpha = __builtin_amdgcn_exp2f(mr0 - mx);
        lr0 *= alpha;
#pragma unroll
        for (int dt = 0; dt < 4; ++dt)
#pragma unroll
          for (int r = 0; r < 4; ++r) oacc0[dt][r] *= alpha;
        mr0 = mx;
      }
      float ps = 0.f;
#pragma unroll
      for (int nt = 0; nt < 4; ++nt) {
#pragma unroll
        for (int r = 0; r < 4; ++r)
          s0[nt][r] = __builtin_amdgcn_exp2f(s0[nt][r] - mr0);
        ps += (s0[nt][0] + s0[nt][1]) + (s0[nt][2] + s0[nt][3]);
      }
      lr0 += ps;
#pragma unroll
      for (int nt = 0; nt < 4; ++nt) {
        uint32_t w0, w1;
        asm("v_cvt_pk_bf16_f32 %0, %1, %2" : "=v"(w0) : "v"(s0[nt][0]), "v"(s0[nt][1]));
        asm("v_cvt_pk_bf16_f32 %0, %1, %2" : "=v"(w1) : "v"(s0[nt][2]), "v"(s0[nt][3]));
        uint2v pw; pw[0] = w0; pw[1] = w1;
        *(uint2v*)(Pb0 + ((nt * 32 + g * 8) ^ sw)) = pw;
      }
    }
    // ---- softmax q-half 1 ----
    {
      float mx = fmaxf(fmaxf(s1[0][0], s1[0][1]), s1[0][2]);
      mx = fmaxf(fmaxf(mx, s1[0][3]), s1[1][0]);
      mx = fmaxf(fmaxf(mx, s1[1][1]), s1[1][2]);
      mx = fmaxf(fmaxf(mx, s1[1][3]), s1[2][0]);
      mx = fmaxf(fmaxf(mx, s1[2][1]), s1[2][2]);
      mx = fmaxf(fmaxf(mx, s1[2][3]), s1[3][0]);
      mx = fmaxf(fmaxf(mx, s1[3][1]), s1[3][2]);
      mx = fmaxf(mx, s1[3][3]);
      mx = fmaxf(mx, __shfl_xor(mx, 16, 64));
      mx = fmaxf(mx, __shfl_xor(mx, 32, 64));
      if (mx > mr1 + 8.0f) {
        float alpha = __builtin_amdgcn_exp2f(mr1 - mx);
        lr1 *= alpha;
#pragma unroll
        for (int dt = 0; dt < 4; ++dt)
#pragma unroll
          for (int r = 0; r < 4; ++r) oacc1[dt][r] *= alpha;
        mr1 = mx;
      }
      float ps = 0.f;
#pragma unroll
      for (int nt = 0; nt < 4; ++nt) {
#pragma unroll
        for (int r = 0; r < 4; ++r)
          s1[nt][r] = __builtin_amdgcn_exp2f(s1[nt][r] - mr1);
        ps += (s1[nt][0] + s1[nt][1]) + (s1[nt][2] + s1[nt][3]);
      }
      lr1 += ps;
#pragma unroll
      for (int nt = 0; nt < 4; ++nt) {
        uint32_t w0, w1;
        asm("v_cvt_pk_bf16_f32 %0, %1, %2" : "=v"(w0) : "v"(s1[nt][0]), "v"(s1[nt][1]));
        asm("v_cvt_pk_bf16_f32 %0, %1, %2" : "=v"(w1) : "v"(s1[nt][2]), "v"(s1[nt][3]));
        uint2v pw; pw[0] = w0; pw[1] = w1;
        *(uint2v*)(Pb1 + ((nt * 32 + g * 8) ^ sw)) = pw;
      }
    }
    // no explicit fence: same-wave DS ops are in-order; compiler inserts the
    // precise lgkmcnt for the may-alias write->read pair.

    // PV transposed: ctx^T += V^T @ P^T; V-frag read once, used for both halves
    __builtin_amdgcn_s_setprio(1);
#pragma unroll
    for (int kb = 0; kb < 2; ++kb) {
      bfrag ap0 = *(const bfrag*)(Pb0 + ((kb * 64 + g * 16) ^ sw));
      bfrag ap1 = *(const bfrag*)(Pb1 + ((kb * 64 + g * 16) ^ sw));
#pragma unroll
      for (int dt = 0; dt < 4; ++dt) {
        int off = ((dt * 16 + c) * 128 + kb * 64 + g * 16) ^ sw;
        bfrag bv = *(const bfrag*)(Vbuf + off);
        oacc0[dt] = __builtin_amdgcn_mfma_f32_16x16x32_bf16(bv, ap0, oacc0[dt], 0, 0, 0);
        oacc1[dt] = __builtin_amdgcn_mfma_f32_16x16x32_bf16(bv, ap1, oacc1[dt], 0, 0, 0);
      }
    }
    __builtin_amdgcn_s_setprio(0);

    __syncthreads();  // drains this wave's stage vmcnt; next tile ready
    cur ^= 1;
  }

  // epilogue: finish l reductions (2 shfls each), write q-rows as float4s
  lr0 += __shfl_xor(lr0, 16, 64);
  lr0 += __shfl_xor(lr0, 32, 64);
  lr1 += __shfl_xor(lr1, 16, 64);
  lr1 += __shfl_xor(lr1, 32, 64);
  float inv0 = 1.0f / lr0, inv1 = 1.0f / lr1;
  size_t orow = rowb + (size_t)qt * 128 + wave * 32 + c;
#pragma unroll
  for (int dt = 0; dt < 4; ++dt) {
    float4v o;
    o[0] = oacc0[dt][0] * inv0; o[1] = oacc0[dt][1] * inv0;
    o[2] = oacc0[dt][2] * inv0; o[3] = oacc0[dt][3] * inv0;
    *(float4v*)&out[orow * HIDDEN + colb + dt * 16 + g * 4] = o;
    float4v p;
    p[0] = oacc1[dt][0] * inv1; p[1] = oacc1[dt][1] * inv1;
    p[2] = oacc1[dt][2] * inv1; p[3] = oacc1[dt][3] * inv1;
    *(float4v*)&out[(orow + 16) * HIDDEN + colb + dt * 16 + g * 4] = p;
  }
}

extern "C" void kernel_launch(void* const* d_in, const int* in_sizes, int n_in,
                              void* d_out, int out_size, void* d_ws, size_t ws_size,
                              hipStream_t stream) {
  const float* x  = (const float*)d_in[0];
  const float* Wq = (const float*)d_in[1];
  const float* bq = (const float*)d_in[2];
  const float* Wk = (const float*)d_in[3];
  const float* bk = (const float*)d_in[4];
  const float* Wv = (const float*)d_in[5];
  const float* bv = (const float*)d_in[6];
  float* out = (float*)d_out;

  uint8_t* ws = (uint8_t*)d_ws;
  const size_t XB = 0;
  const size_t WT = XB + (size_t)MTOT * HIDDEN * 2;        // 16 MB
  const size_t QB = WT + (size_t)3 * HIDDEN * HIDDEN * 2;  // +6 MB
  const size_t KB = QB + (size_t)MTOT * HIDDEN * 2;
  const size_t VB = KB + (size_t)MTOT * HIDDEN * 2;        // total ~70 MB
  uint16_t* Xb = (uint16_t*)(ws + XB);
  uint16_t* Wt = (uint16_t*)(ws + WT);
  uint16_t* Qb = (uint16_t*)(ws + QB);
  uint16_t* Kb = (uint16_t*)(ws + KB);
  uint16_t* Vb = (uint16_t*)(ws + VB);   // V^T [64][64][2048]

  cvt_kernel<<<dim3(4096 + 768), 256, 0, stream>>>(x, Wq, Wk, Wv, Xb, Wt);
  gemm_qkv_kernel<<<dim3(64, 8, 3), 256, 0, stream>>>(Xb, Wt, bq, bk, bv, Qb, Kb, Vb);
  attn_kernel<<<dim3(1024), 256, 0, stream>>>(Qb, Kb, Vb, out);
}

// Round 9
// 258.178 us; speedup vs baseline: 1.1027x; 1.0569x over previous
//
#include <hip/hip_runtime.h>
#include <hip/hip_bf16.h>
#include <cstdint>

#define HIDDEN 1024
#define HEADS 16
#define HDIM 64
#define BATCH 4
#define SEQ 2048
#define MTOT (BATCH * SEQ)   // 8192

typedef __attribute__((ext_vector_type(8))) short bfrag;   // 8 bf16 (A/B frag)
typedef __attribute__((ext_vector_type(4))) float cfrag;   // 4 f32 (C/D frag)
typedef __attribute__((ext_vector_type(4))) float float4v;
typedef __attribute__((ext_vector_type(4))) unsigned short ushort4v;
typedef __attribute__((ext_vector_type(2))) unsigned int uint2v;

#define AS1 __attribute__((address_space(1)))
#define AS3 __attribute__((address_space(3)))

__device__ __forceinline__ void gl_lds16(const void* g, void* l) {
  // async global->LDS, 16B per lane; LDS dest = wave-uniform base + lane*16
  __builtin_amdgcn_global_load_lds((AS1 void*)g, (AS3 void*)l, 16, 0, 0);
}

__device__ __forceinline__ uint16_t f2b(float f) {  // f32 -> bf16 bits, RNE
  union { float f; uint32_t u; } v; v.f = f;
  uint32_t u = v.u;
  return (uint16_t)((u + 0x7FFFu + ((u >> 16) & 1u)) >> 16);
}

// ---------------- kernel 1: fused converts ----------------
// blocks [0,4096): x fp32 -> bf16;  blocks [4096,4864): W -> Wt [N][K] bf16 x3
__global__ __launch_bounds__(256) void cvt_kernel(
    const float* __restrict__ x, const float* __restrict__ W0,
    const float* __restrict__ W1, const float* __restrict__ W2,
    uint16_t* __restrict__ Xb, uint16_t* __restrict__ Wt) {
  int bid = blockIdx.x;
  if (bid < 4096) {
    int i = bid * 256 + threadIdx.x;          // i < 1048576 = MTOT*HIDDEN/8
    float4v a = ((const float4v*)x)[2 * i];
    float4v b = ((const float4v*)x)[2 * i + 1];
    bfrag o;
    o[0] = (short)f2b(a[0]); o[1] = (short)f2b(a[1]);
    o[2] = (short)f2b(a[2]); o[3] = (short)f2b(a[3]);
    o[4] = (short)f2b(b[0]); o[5] = (short)f2b(b[1]);
    o[6] = (short)f2b(b[2]); o[7] = (short)f2b(b[3]);
    ((bfrag*)Xb)[i] = o;
    return;
  }
  int id = bid - 4096;                        // [0,768)
  int z = id >> 8, rem = id & 255;
  const float* W = z == 0 ? W0 : (z == 1 ? W1 : W2);
  uint16_t* out = Wt + (size_t)z * HIDDEN * HIDDEN;
  __shared__ float tile[64][65];
  int n0 = (rem & 15) * 64, k0 = (rem >> 4) * 64;
  int t = threadIdx.x;
  int r = t >> 2, cq = (t & 3) * 16;
#pragma unroll
  for (int i = 0; i < 16; i += 4) {
    float4v v = *(const float4v*)&W[(size_t)(k0 + r) * HIDDEN + n0 + cq + i];
    tile[r][cq + i + 0] = v[0]; tile[r][cq + i + 1] = v[1];
    tile[r][cq + i + 2] = v[2]; tile[r][cq + i + 3] = v[3];
  }
  __syncthreads();
  bfrag o0, o1;
#pragma unroll
  for (int i = 0; i < 8; ++i) o0[i] = (short)f2b(tile[cq + i][r]);
#pragma unroll
  for (int i = 0; i < 8; ++i) o1[i] = (short)f2b(tile[cq + 8 + i][r]);
  *(bfrag*)&out[(size_t)(n0 + r) * HIDDEN + k0 + cq] = o0;
  *(bfrag*)&out[(size_t)(n0 + r) * HIDDEN + k0 + cq + 8] = o1;
}

// ---------------- kernel 2: FUSED QKV projection GEMM ----------------
// One block computes the 128x128 tile of Q, K, AND V^T: X tile staged once,
// A-fragments read once, 48 MFMAs per K-step per wave (3x density of split).
// Q scaled by 0.125*log2(e); V written transposed [64 bh][64 d][2048 s].
__global__ __launch_bounds__(256, 2) void gemm_qkv_kernel(
    const uint16_t* __restrict__ X, const uint16_t* __restrict__ Wt,
    const float* __restrict__ b0, const float* __restrict__ b1,
    const float* __restrict__ b2,
    uint16_t* __restrict__ Qo, uint16_t* __restrict__ Ko, uint16_t* __restrict__ Vo) {
  __shared__ uint16_t As[128 * 32];
  __shared__ uint16_t Bs[3][128 * 32];

  int m0 = blockIdx.x * 128, n0 = blockIdx.y * 128;
  int tid = threadIdx.x;
  int wave = tid >> 6, lane = tid & 63;
  int wm = wave >> 1, wn = wave & 1;       // 2x2 wave grid, 64x64 per wave
  int g = lane >> 4, c = lane & 15;
  int sr = lane >> 2;                       // staging: row within 16-row chunk
  int sc = (lane & 3) * 8;                  // staging: k offset (8 bf16 = 16B)

  cfrag accQ[4][4], accK[4][4], accV[4][4];
#pragma unroll
  for (int i = 0; i < 4; ++i)
#pragma unroll
    for (int j = 0; j < 4; ++j) {
      accQ[i][j] = cfrag{0.f, 0.f, 0.f, 0.f};
      accK[i][j] = cfrag{0.f, 0.f, 0.f, 0.f};
      accV[i][j] = cfrag{0.f, 0.f, 0.f, 0.f};
    }

  for (int kt = 0; kt < HIDDEN / 32; ++kt) {
    int kc = kt * 32 + sc;
#pragma unroll
    for (int i = 0; i < 2; ++i) {
      int rowA = (i * 4 + wave) * 16;  // wave-uniform
      gl_lds16(&X[(size_t)(m0 + rowA + sr) * HIDDEN + kc], &As[rowA * 32]);
      gl_lds16(&Wt[(size_t)(n0 + rowA + sr) * HIDDEN + kc],
               &Bs[0][rowA * 32]);
      gl_lds16(&Wt[(size_t)HIDDEN * HIDDEN + (size_t)(n0 + rowA + sr) * HIDDEN + kc],
               &Bs[1][rowA * 32]);
      gl_lds16(&Wt[(size_t)2 * HIDDEN * HIDDEN + (size_t)(n0 + rowA + sr) * HIDDEN + kc],
               &Bs[2][rowA * 32]);
    }
    __syncthreads();  // vmcnt(0) drained before barrier -> LDS ready
    bfrag af[4];
#pragma unroll
    for (int mt = 0; mt < 4; ++mt)
      af[mt] = *(const bfrag*)&As[(wm * 64 + mt * 16 + c) * 32 + g * 8];
    __builtin_amdgcn_s_setprio(1);
    {
      bfrag bf[4];
#pragma unroll
      for (int nt = 0; nt < 4; ++nt)
        bf[nt] = *(const bfrag*)&Bs[0][(wn * 64 + nt * 16 + c) * 32 + g * 8];
#pragma unroll
      for (int mt = 0; mt < 4; ++mt)
#pragma unroll
        for (int nt = 0; nt < 4; ++nt)
          accQ[mt][nt] = __builtin_amdgcn_mfma_f32_16x16x32_bf16(af[mt], bf[nt],
                                                                 accQ[mt][nt], 0, 0, 0);
    }
    {
      bfrag bf[4];
#pragma unroll
      for (int nt = 0; nt < 4; ++nt)
        bf[nt] = *(const bfrag*)&Bs[1][(wn * 64 + nt * 16 + c) * 32 + g * 8];
#pragma unroll
      for (int mt = 0; mt < 4; ++mt)
#pragma unroll
        for (int nt = 0; nt < 4; ++nt)
          accK[mt][nt] = __builtin_amdgcn_mfma_f32_16x16x32_bf16(af[mt], bf[nt],
                                                                 accK[mt][nt], 0, 0, 0);
    }
    {
      bfrag bf[4];
#pragma unroll
      for (int nt = 0; nt < 4; ++nt)
        bf[nt] = *(const bfrag*)&Bs[2][(wn * 64 + nt * 16 + c) * 32 + g * 8];
#pragma unroll
      for (int mt = 0; mt < 4; ++mt)
#pragma unroll
        for (int nt = 0; nt < 4; ++nt)
          accV[mt][nt] = __builtin_amdgcn_mfma_f32_16x16x32_bf16(af[mt], bf[nt],
                                                                 accV[mt][nt], 0, 0, 0);
    }
    __builtin_amdgcn_s_setprio(0);
    __syncthreads();  // all waves done with LDS before next stage
  }

  // ---- Q epilogue (exp2-domain scale folded) ----
  {
    const float sc_ = 0.125f * 1.44269504088896f;
#pragma unroll
    for (int nt = 0; nt < 4; ++nt) {
      int n = n0 + wn * 64 + nt * 16 + c;
      float bb = b0[n];
#pragma unroll
      for (int mt = 0; mt < 4; ++mt) {
        int mb = m0 + wm * 64 + mt * 16 + g * 4;
#pragma unroll
        for (int r = 0; r < 4; ++r)
          Qo[(size_t)(mb + r) * HIDDEN + n] = f2b((accQ[mt][nt][r] + bb) * sc_);
      }
    }
  }
  // ---- K epilogue ----
  {
#pragma unroll
    for (int nt = 0; nt < 4; ++nt) {
      int n = n0 + wn * 64 + nt * 16 + c;
      float bb = b1[n];
#pragma unroll
      for (int mt = 0; mt < 4; ++mt) {
        int mb = m0 + wm * 64 + mt * 16 + g * 4;
#pragma unroll
        for (int r = 0; r < 4; ++r)
          Ko[(size_t)(mb + r) * HIDDEN + n] = f2b(accK[mt][nt][r] + bb);
      }
    }
  }
  // ---- V^T epilogue: [bh][d][s] ----
  {
    int bb_ = m0 >> 11;                 // batch (m0 128-aligned, 2048%128==0)
    int s0 = (m0 & 2047) + wm * 64;
#pragma unroll
    for (int nt = 0; nt < 4; ++nt) {
      int n = n0 + wn * 64 + nt * 16 + c;
      int h = n >> 6, d = n & 63;
      float bb = b2[n];
      size_t base = ((size_t)(bb_ * 16 + h) * 64 + d) * SEQ;
#pragma unroll
      for (int mt = 0; mt < 4; ++mt) {
        int s = s0 + mt * 16 + g * 4;
        ushort4v pk;
        pk[0] = f2b(accV[mt][nt][0] + bb);
        pk[1] = f2b(accV[mt][nt][1] + bb);
        pk[2] = f2b(accV[mt][nt][2] + bb);
        pk[3] = f2b(accV[mt][nt][3] + bb);
        *(ushort4v*)&Vo[base + s] = pk;
      }
    }
  }
}

// ---------------- kernel 3: flash attention (QBLK=128, transposed, exp2) -----
// Q,K bf16 [8192][1024]; VT bf16 [64][64][2048]; out fp32 [8192][1024]
// 4 waves x 32 q-rows each; S^T = mfma(K,Q) log2-domain; ctx^T = mfma(V^T,P).
// Lane owns q-rows {c, 16+c} of its wave; softmax in-lane + 2 shfls.
__global__ __launch_bounds__(256, 3) void attn_kernel(
    const uint16_t* __restrict__ Q, const uint16_t* __restrict__ K,
    const uint16_t* __restrict__ VT, float* __restrict__ out) {
  __shared__ uint16_t Ks[2][64 * 64];    // K tile, XOR-swizzled content
  __shared__ uint16_t Vs[2][64 * 64];    // V^T tile [d][s], XOR-swizzled content
  __shared__ __align__(16) uint16_t Pl[4][32][64];  // per-wave P [q][kv], XOR-swz

  // XCD-aware swizzle: 1024 blocks -> each XCD covers 4 heads (KV L2-resident)
  int bid = blockIdx.x;
  int wg = (bid & 7) * 128 + (bid >> 3);
  int bh = wg >> 4, qt = wg & 15;
  int b = bh >> 4, h = bh & 15;
  int tid = threadIdx.x, wave = tid >> 6, lane = tid & 63;
  int g = lane >> 4, c = lane & 15;
  size_t rowb = (size_t)b * SEQ;
  int colb = h * HDIM;
  const uint16_t* Kh = K + rowb * HIDDEN + colb;          // [s][d] stride 1024
  const uint16_t* Vh = VT + (size_t)bh * HDIM * SEQ;      // [d][s] stride 2048

  // staging: lane covers 16B; pre-swizzled global col so the LINEAR
  // global_load_lds write lands XOR-swizzled (rule #21 both-sides)
  int r8 = lane >> 3, c8 = lane & 7;
  int scol = ((c8 ^ r8) << 3);           // element offset 0..56
  int sbrow = (wave & 1) * 32;           // this wave's 4 calls start here

  // Q fragments (B-operand: col=lane&15=q, k=g*8..) for both q-halves
  int qrow = qt * 128 + wave * 32 + c;
  bfrag aq0[2], aq1[2];
#pragma unroll
  for (int kb = 0; kb < 2; ++kb) {
    aq0[kb] = *(const bfrag*)&Q[(rowb + qrow) * HIDDEN + colb + kb * 32 + g * 8];
    aq1[kb] = *(const bfrag*)&Q[(rowb + qrow + 16) * HIDDEN + colb + kb * 32 + g * 8];
  }

  float mr0 = -INFINITY, lr0 = 0.f;      // per-lane state, q-half 0 (row c)
  float mr1 = -INFINITY, lr1 = 0.f;      // q-half 1 (row 16+c)
  cfrag oacc0[4], oacc1[4];              // ctx^T: d = dt*16+g*4+r
#pragma unroll
  for (int dt = 0; dt < 4; ++dt) {
    oacc0[dt] = cfrag{0.f, 0.f, 0.f, 0.f};
    oacc1[dt] = cfrag{0.f, 0.f, 0.f, 0.f};
  }

  // prologue: stage tile 0 into buf 0 (waves 0-1: K rows, waves 2-3: V rows)
  if (wave < 2) {
#pragma unroll
    for (int j = 0; j < 4; ++j) {
      int rl = sbrow + j * 8;
      gl_lds16(&Kh[(size_t)(rl + r8) * HIDDEN + scol], &Ks[0][rl * 64]);
    }
  } else {
#pragma unroll
    for (int j = 0; j < 4; ++j) {
      int rl = sbrow + j * 8;
      gl_lds16(&Vh[(size_t)(rl + r8) * SEQ + scol], &Vs[0][rl * 64]);
    }
  }
  __syncthreads();  // compiler drains vmcnt before barrier -> tile 0 ready

  int cur = 0;
  int sw = (c & 7) << 4;                 // read-side byte swizzle (K/V and P)
  uint8_t* Pb0 = (uint8_t*)Pl + wave * 4096 + c * 128;        // P row q=c
  uint8_t* Pb1 = Pb0 + 16 * 128;                              // P row q=16+c

  for (int t = 0; t < 32; ++t) {
    int j0 = t * 64;
    // issue next-tile stage first; latency hides under this tile's compute
    if (t < 31) {
      int jn = j0 + 64;
      if (wave < 2) {
#pragma unroll
        for (int j = 0; j < 4; ++j) {
          int rl = sbrow + j * 8;
          gl_lds16(&Kh[(size_t)(jn + rl + r8) * HIDDEN + scol],
                   &Ks[cur ^ 1][rl * 64]);
        }
      } else {
#pragma unroll
        for (int j = 0; j < 4; ++j) {
          int rl = sbrow + j * 8;
          gl_lds16(&Vh[(size_t)(rl + r8) * SEQ + jn + scol],
                   &Vs[cur ^ 1][rl * 64]);
        }
      }
    }

    const uint8_t* Kbuf = (const uint8_t*)Ks[cur];
    const uint8_t* Vbuf = (const uint8_t*)Vs[cur];

    // S^T = K @ Q^T, both q-halves; K-frag read once, used twice
    cfrag s0[4], s1[4];
#pragma unroll
    for (int nt = 0; nt < 4; ++nt) {
      s0[nt] = cfrag{0.f, 0.f, 0.f, 0.f};
      s1[nt] = cfrag{0.f, 0.f, 0.f, 0.f};
    }
    __builtin_amdgcn_s_setprio(1);
#pragma unroll
    for (int kb = 0; kb < 2; ++kb) {
#pragma unroll
      for (int nt = 0; nt < 4; ++nt) {
        int off = ((nt * 16 + c) * 128 + kb * 64 + g * 16) ^ sw;
        bfrag bk = *(const bfrag*)(Kbuf + off);
        s0[nt] = __builtin_amdgcn_mfma_f32_16x16x32_bf16(bk, aq0[kb], s0[nt], 0, 0, 0);
        s1[nt] = __builtin_amdgcn_mfma_f32_16x16x32_bf16(bk, aq1[kb], s1[nt], 0, 0, 0);
      }
    }
    __builtin_amdgcn_s_setprio(0);

    // ---- softmax q-half 0 (log2 domain) ----
    {
      float mx = fmaxf(fmaxf(s0[0][0], s0[0][1]), s0[0][2]);
      mx = fmaxf(fmaxf(mx, s0[0][3]), s0[1][0]);
      mx = fmaxf(fmaxf(mx, s0[1][1]), s0[1][2]);
      mx = fmaxf(fmaxf(mx, s0[1][3]), s0[2][0]);
      mx = fmaxf(fmaxf(mx, s0[2][1]), s0[2][2]);
      mx = fmaxf(fmaxf(mx, s0[2][3]), s0[3][0]);
      mx = fmaxf(fmaxf(mx, s0[3][1]), s0[3][2]);
      mx = fmaxf(mx, s0[3][3]);
      mx = fmaxf(mx, __shfl_xor(mx, 16, 64));
      mx = fmaxf(mx, __shfl_xor(mx, 32, 64));
      if (mx > mr0 + 8.0f) {                   // defer-max (T13)
        float alpha = __builtin_amdgcn_exp2f(mr0 - mx);
        lr0 *= alpha;
#pragma unroll
        for (int dt = 0; dt < 4; ++dt)
#pragma unroll
          for (int r = 0; r < 4; ++r) oacc0[dt][r] *= alpha;
        mr0 = mx;
      }
      float ps = 0.f;
#pragma unroll
      for (int nt = 0; nt < 4; ++nt) {
#pragma unroll
        for (int r = 0; r < 4; ++r)
          s0[nt][r] = __builtin_amdgcn_exp2f(s0[nt][r] - mr0);
        ps += (s0[nt][0] + s0[nt][1]) + (s0[nt][2] + s0[nt][3]);
      }
      lr0 += ps;
#pragma unroll
      for (int nt = 0; nt < 4; ++nt) {
        uint32_t w0, w1;
        asm("v_cvt_pk_bf16_f32 %0, %1, %2" : "=v"(w0) : "v"(s0[nt][0]), "v"(s0[nt][1]));
        asm("v_cvt_pk_bf16_f32 %0, %1, %2" : "=v"(w1) : "v"(s0[nt][2]), "v"(s0[nt][3]));
        uint2v pw; pw[0] = w0; pw[1] = w1;
        *(uint2v*)(Pb0 + ((nt * 32 + g * 8) ^ sw)) = pw;
      }
    }
    // ---- softmax q-half 1 ----
    {
      float mx = fmaxf(fmaxf(s1[0][0], s1[0][1]), s1[0][2]);
      mx = fmaxf(fmaxf(mx, s1[0][3]), s1[1][0]);
      mx = fmaxf(fmaxf(mx, s1[1][1]), s1[1][2]);
      mx = fmaxf(fmaxf(mx, s1[1][3]), s1[2][0]);
      mx = fmaxf(fmaxf(mx, s1[2][1]), s1[2][2]);
      mx = fmaxf(fmaxf(mx, s1[2][3]), s1[3][0]);
      mx = fmaxf(fmaxf(mx, s1[3][1]), s1[3][2]);
      mx = fmaxf(mx, s1[3][3]);
      mx = fmaxf(mx, __shfl_xor(mx, 16, 64));
      mx = fmaxf(mx, __shfl_xor(mx, 32, 64));
      if (mx > mr1 + 8.0f) {
        float alpha = __builtin_amdgcn_exp2f(mr1 - mx);
        lr1 *= alpha;
#pragma unroll
        for (int dt = 0; dt < 4; ++dt)
#pragma unroll
          for (int r = 0; r < 4; ++r) oacc1[dt][r] *= alpha;
        mr1 = mx;
      }
      float ps = 0.f;
#pragma unroll
      for (int nt = 0; nt < 4; ++nt) {
#pragma unroll
        for (int r = 0; r < 4; ++r)
          s1[nt][r] = __builtin_amdgcn_exp2f(s1[nt][r] - mr1);
        ps += (s1[nt][0] + s1[nt][1]) + (s1[nt][2] + s1[nt][3]);
      }
      lr1 += ps;
#pragma unroll
      for (int nt = 0; nt < 4; ++nt) {
        uint32_t w0, w1;
        asm("v_cvt_pk_bf16_f32 %0, %1, %2" : "=v"(w0) : "v"(s1[nt][0]), "v"(s1[nt][1]));
        asm("v_cvt_pk_bf16_f32 %0, %1, %2" : "=v"(w1) : "v"(s1[nt][2]), "v"(s1[nt][3]));
        uint2v pw; pw[0] = w0; pw[1] = w1;
        *(uint2v*)(Pb1 + ((nt * 32 + g * 8) ^ sw)) = pw;
      }
    }
    // no explicit fence: same-wave DS ops are in-order; compiler inserts the
    // precise lgkmcnt for the may-alias write->read pair.

    // PV transposed: ctx^T += V^T @ P^T; V-frag read once, used for both halves
    __builtin_amdgcn_s_setprio(1);
#pragma unroll
    for (int kb = 0; kb < 2; ++kb) {
      bfrag ap0 = *(const bfrag*)(Pb0 + ((kb * 64 + g * 16) ^ sw));
      bfrag ap1 = *(const bfrag*)(Pb1 + ((kb * 64 + g * 16) ^ sw));
#pragma unroll
      for (int dt = 0; dt < 4; ++dt) {
        int off = ((dt * 16 + c) * 128 + kb * 64 + g * 16) ^ sw;
        bfrag bv = *(const bfrag*)(Vbuf + off);
        oacc0[dt] = __builtin_amdgcn_mfma_f32_16x16x32_bf16(bv, ap0, oacc0[dt], 0, 0, 0);
        oacc1[dt] = __builtin_amdgcn_mfma_f32_16x16x32_bf16(bv, ap1, oacc1[dt], 0, 0, 0);
      }
    }
    __builtin_amdgcn_s_setprio(0);

    __syncthreads();  // drains this wave's stage vmcnt; next tile ready
    cur ^= 1;
  }

  // epilogue: finish l reductions (2 shfls each), write q-rows as float4s
  lr0 += __shfl_xor(lr0, 16, 64);
  lr0 += __shfl_xor(lr0, 32, 64);
  lr1 += __shfl_xor(lr1, 16, 64);
  lr1 += __shfl_xor(lr1, 32, 64);
  float inv0 = 1.0f / lr0, inv1 = 1.0f / lr1;
  size_t orow = rowb + (size_t)qt * 128 + wave * 32 + c;
#pragma unroll
  for (int dt = 0; dt < 4; ++dt) {
    float4v o;
    o[0] = oacc0[dt][0] * inv0; o[1] = oacc0[dt][1] * inv0;
    o[2] = oacc0[dt][2] * inv0; o[3] = oacc0[dt][3] * inv0;
    *(float4v*)&out[orow * HIDDEN + colb + dt * 16 + g * 4] = o;
    float4v p;
    p[0] = oacc1[dt][0] * inv1; p[1] = oacc1[dt][1] * inv1;
    p[2] = oacc1[dt][2] * inv1; p[3] = oacc1[dt][3] * inv1;
    *(float4v*)&out[(orow + 16) * HIDDEN + colb + dt * 16 + g * 4] = p;
  }
}

extern "C" void kernel_launch(void* const* d_in, const int* in_sizes, int n_in,
                              void* d_out, int out_size, void* d_ws, size_t ws_size,
                              hipStream_t stream) {
  const float* x  = (const float*)d_in[0];
  const float* Wq = (const float*)d_in[1];
  const float* bq = (const float*)d_in[2];
  const float* Wk = (const float*)d_in[3];
  const float* bk = (const float*)d_in[4];
  const float* Wv = (const float*)d_in[5];
  const float* bv = (const float*)d_in[6];
  float* out = (float*)d_out;

  uint8_t* ws = (uint8_t*)d_ws;
  const size_t XB = 0;
  const size_t WT = XB + (size_t)MTOT * HIDDEN * 2;        // 16 MB
  const size_t QB = WT + (size_t)3 * HIDDEN * HIDDEN * 2;  // +6 MB
  const size_t KB = QB + (size_t)MTOT * HIDDEN * 2;
  const size_t VB = KB + (size_t)MTOT * HIDDEN * 2;        // total ~70 MB
  uint16_t* Xb = (uint16_t*)(ws + XB);
  uint16_t* Wt = (uint16_t*)(ws + WT);
  uint16_t* Qb = (uint16_t*)(ws + QB);
  uint16_t* Kb = (uint16_t*)(ws + KB);
  uint16_t* Vb = (uint16_t*)(ws + VB);   // V^T [64][64][2048]

  cvt_kernel<<<dim3(4096 + 768), 256, 0, stream>>>(x, Wq, Wk, Wv, Xb, Wt);
  gemm_qkv_kernel<<<dim3(64, 8), 256, 0, stream>>>(Xb, Wt, bq, bk, bv, Qb, Kb, Vb);
  attn_kernel<<<dim3(1024), 256, 0, stream>>>(Qb, Kb, Vb, out);
}